// Round 10
// baseline (176.585 us; speedup 1.0000x reference)
//
#include <hip/hip_runtime.h>
#include <hip/hip_bf16.h>

#define BB 2
#define SS 2048
#define DD 1024
#define HH 16
#define DHD 64

typedef __attribute__((ext_vector_type(8))) short short8;   // 8 bf16 = 4 VGPRs
typedef __attribute__((ext_vector_type(4))) float floatx4;  // MFMA 16x16 C/D
typedef __attribute__((ext_vector_type(16))) float floatx16; // MFMA 32x32 C/D
typedef __attribute__((ext_vector_type(4))) unsigned short ushortx4;

static __device__ __forceinline__ unsigned short f2bf(float f) {
    union { __hip_bfloat16 h; unsigned short u; } cv;
    cv.h = __float2bfloat16(f);
    return cv.u;
}

// async global->LDS 16B copy; LDS dest MUST be wave-uniform base + lane*16
typedef __attribute__((address_space(1))) const unsigned int* gas_t;
typedef __attribute__((address_space(3))) unsigned int* las_t;
static __device__ __forceinline__ void g2l16(const void* g, void* l) {
    __builtin_amdgcn_global_load_lds((gas_t)g, (las_t)l, 16, 0, 0);
}

// XOR swizzle: LDS[row][c8] holds global[row][c8 ^ (row&7)] (c8 = 16B chunk).
#define SW(row, c8) ((c8) ^ ((row) & 7))

// pack 2 f32 -> 1 u32 of 2 bf16 (no builtin on gfx950; T12 recipe)
static __device__ __forceinline__ unsigned cvt_pk_bf16(float lo, float hi) {
    unsigned r;
    asm("v_cvt_pk_bf16_f32 %0, %1, %2" : "=v"(r) : "v"(lo), "v"(hi));
    return r;
}
static __device__ __forceinline__ void pl32_swap(unsigned &a, unsigned &b) {
    asm("v_permlane32_swap_b32 %0, %1" : "+v"(a), "+v"(b));
}

// ---------------------------------------------------------------------------
// Prep kernel v2: residual copy MOVED into attn's grid (it has no deps and
// attn runs at 5% HBM with an idle causal tail -- the copy hides there).
// Grid 3072: [0,2048) x->bf16, [2048,2816) W_QKV transpose, [2816,3072) W_O.
// ---------------------------------------------------------------------------
__global__ __launch_bounds__(256) void prep(
        const float* __restrict__ x, unsigned short* __restrict__ xb,
        const float* __restrict__ WQ, const float* __restrict__ WK,
        const float* __restrict__ WV, unsigned short* __restrict__ Wt,
        const float* __restrict__ WO, unsigned short* __restrict__ WtO) {
    __shared__ float tile[64][65];
    const int bid = blockIdx.x;
    const int t = threadIdx.x;

    if (bid < 2048) {                              // x -> bf16
        size_t i = ((size_t)bid * 256 + t) * 8;
        const float4* src4 = (const float4*)(x + i);
        float4 a = src4[0], b = src4[1];
        short8 o;
        o[0] = (short)f2bf(a.x); o[1] = (short)f2bf(a.y);
        o[2] = (short)f2bf(a.z); o[3] = (short)f2bf(a.w);
        o[4] = (short)f2bf(b.x); o[5] = (short)f2bf(b.y);
        o[6] = (short)f2bf(b.z); o[7] = (short)f2bf(b.w);
        *(short8*)(xb + i) = o;
    } else if (bid < 2816) {                       // W_QKV transpose
        int u = bid - 2048;
        const int d0 = (u & 15) * 64;
        const int h  = (u >> 4) & 15;
        const int which = u >> 8;
        const float* W = (which == 0) ? WQ : (which == 1) ? WK : WV;
        const float* src = W + (size_t)h * DD * DHD;
#pragma unroll
        for (int i = 0; i < 16; i++) {
            int idx = i * 256 + t;
            int r = idx >> 6, c = idx & 63;
            tile[r][c] = src[(size_t)(d0 + r) * DHD + c];
        }
        __syncthreads();
        unsigned short* dst = Wt + ((size_t)which * 1024 + h * 64) * DD;
#pragma unroll
        for (int i = 0; i < 16; i++) {
            int idx = i * 256 + t;
            int e = idx >> 6, d = idx & 63;
            dst[(size_t)e * DD + d0 + d] = f2bf(tile[d][e]);
        }
    } else {                                       // W_O transpose
        int u = bid - 2816;
        const int k0 = (u & 15) * 64;
        const int n0 = (u >> 4) * 64;
#pragma unroll
        for (int i = 0; i < 16; i++) {
            int idx = i * 256 + t;
            int r = idx >> 6, c = idx & 63;
            tile[r][c] = WO[(size_t)(k0 + r) * DD + n0 + c];
        }
        __syncthreads();
#pragma unroll
        for (int i = 0; i < 16; i++) {
            int idx = i * 256 + t;
            int n = idx >> 6, kk = idx & 63;
            WtO[(size_t)(n0 + n) * DD + k0 + kk] = f2bf(tile[kk][n]);
        }
    }
}

// ---------------------------------------------------------------------------
// QKV MFMA GEMM (round-9 proven form, unchanged): 128x128 tiles, 2-phase
// double-buffered prefetch, one __syncthreads per K-step. Q pre-scale folds
// log2(e): 0.125 * 1.4426950 = 0.18033688.
// ---------------------------------------------------------------------------
__global__ __launch_bounds__(256) void qkv_mfma(const unsigned short* __restrict__ xb,
        const unsigned short* __restrict__ Wt,
        const float* __restrict__ bQ, const float* __restrict__ bK,
        const float* __restrict__ bV,
        unsigned short* __restrict__ oq, unsigned short* __restrict__ ok,
        unsigned short* __restrict__ ov) {
    __shared__ unsigned short smem[32768];         // A0|A1|B0|B1, 8192 hw each

    const int m0 = blockIdx.x * 128;
    const int y  = blockIdx.y;
    const int which = y >> 3;
    const int h0 = (y & 7) * 2;
    const float* bias = (which == 0) ? bQ : (which == 1) ? bK : bV;
    unsigned short* ob = (which == 0) ? oq : (which == 1) ? ok : ov;
    const float scale = (which == 0) ? 0.18033688f : 1.0f;  // 1/8 * log2(e)
    const unsigned short* Wb = Wt + (size_t)y * 128 * DD;

    const int t = threadIdx.x;
    const int lane = t & 63, w = t >> 6;
    const int l15 = lane & 15, quad = lane >> 4;

    floatx4 acc[2][8];
#pragma unroll
    for (int mt = 0; mt < 2; mt++)
#pragma unroll
        for (int nt = 0; nt < 8; nt++) acc[mt][nt] = floatx4{0.f, 0.f, 0.f, 0.f};

    // prologue: stage k0=0 into buffer 0
#pragma unroll
    for (int i = 0; i < 4; i++) {
        int c = i * 256 + t;
        int row = c >> 3, c8 = c & 7;
        g2l16(xb + (size_t)(m0 + row) * DD + SW(row, c8) * 8, smem + c * 8);
        g2l16(Wb + (size_t)row * DD + SW(row, c8) * 8, smem + 16384 + c * 8);
    }

    int buf = 0;
    for (int k0 = 0; k0 < DD; k0 += 64) {
        __syncthreads();                           // tile k0 staged; buf reuse safe
        if (k0 + 64 < DD) {                        // prefetch k0+64 under compute
            const int nb = buf ^ 1;
#pragma unroll
            for (int i = 0; i < 4; i++) {
                int c = i * 256 + t;
                int row = c >> 3, c8 = c & 7;
                g2l16(xb + (size_t)(m0 + row) * DD + k0 + 64 + SW(row, c8) * 8,
                      smem + nb * 8192 + c * 8);
                g2l16(Wb + (size_t)row * DD + k0 + 64 + SW(row, c8) * 8,
                      smem + 16384 + nb * 8192 + c * 8);
            }
        }
        const unsigned short* As = smem + buf * 8192;
        const unsigned short* Bs = smem + 16384 + buf * 8192;
#pragma unroll
        for (int ks = 0; ks < 2; ks++) {
            short8 af[2], bf[8];
#pragma unroll
            for (int mt = 0; mt < 2; mt++)
                af[mt] = *(const short8*)(As + (w * 32 + mt * 16 + l15) * 64 +
                                          SW(l15, ks * 4 + quad) * 8);
#pragma unroll
            for (int nt = 0; nt < 8; nt++)
                bf[nt] = *(const short8*)(Bs + (nt * 16 + l15) * 64 +
                                          SW(l15, ks * 4 + quad) * 8);
#pragma unroll
            for (int mt = 0; mt < 2; mt++)
#pragma unroll
                for (int nt = 0; nt < 8; nt++)
                    acc[mt][nt] = __builtin_amdgcn_mfma_f32_16x16x32_bf16(
                        af[mt], bf[nt], acc[mt][nt], 0, 0, 0);
        }
        buf ^= 1;
    }
    __syncthreads();                               // before epilogue LDS reuse

    if (which == 2) {
        // V: transpose block tile in LDS, store V^T [B][H][64][S] coalesced.
        unsigned short* T = smem;                  // 128(n) x 132 stride
#pragma unroll
        for (int mt = 0; mt < 2; mt++)
#pragma unroll
            for (int r = 0; r < 4; r++) {
                int mloc = w * 32 + mt * 16 + quad * 4 + r;
#pragma unroll
                for (int nt = 0; nt < 8; nt++) {
                    int n = nt * 16 + l15;
                    int h = h0 + (n >> 6), e = n & 63;
                    T[n * 132 + mloc] = f2bf(acc[mt][nt][r] + bias[h * DHD + e]);
                }
            }
        __syncthreads();
        const int b = m0 >> 11;
        const int s_base = m0 & (SS - 1);
#pragma unroll
        for (int i = 0; i < 8; i++) {
            int u = i * 256 + t;
            int row = u >> 4, c8 = u & 15;
            int h = h0 + (row >> 6), e = row & 63;
            *(short8*)(ov + (((size_t)b * HH + h) * DHD + e) * SS + s_base + c8 * 8) =
                *(const short8*)(T + row * 132 + c8 * 8);
        }
    } else {
#pragma unroll
        for (int mt = 0; mt < 2; mt++) {
#pragma unroll
            for (int r = 0; r < 4; r++) {
                int m = m0 + w * 32 + mt * 16 + quad * 4 + r;
                int b = m >> 11, s = m & (SS - 1);
#pragma unroll
                for (int nt = 0; nt < 8; nt++) {
                    int h = h0 + (nt >> 2);
                    int e = (nt & 3) * 16 + l15;
                    float v = (acc[mt][nt][r] + bias[h * DHD + e]) * scale;
                    ob[(((size_t)b * HH + h) * SS + s) * DHD + e] = f2bf(v);
                }
            }
        }
    }
}

// ---------------------------------------------------------------------------
// MFMA flash attention v8: round-9 structure (LDS-staged, diagonal peel,
// setprio clusters, exp2) + 512 residual-copy blocks appended to the grid
// (i0 >= 512). Copy blocks dispatch after attention blocks and backfill the
// causal tail's idle CUs, hiding the 33.5 MB residual passthrough under
// attn compute (attn runs at only ~5% HBM).
// ---------------------------------------------------------------------------
#define KVT 128
__global__ __launch_bounds__(512, 4) void attn(const unsigned short* __restrict__ q,
        const unsigned short* __restrict__ k, const unsigned short* __restrict__ vt,
        unsigned short* __restrict__ z,
        const float4* __restrict__ residual4, float4* __restrict__ out4) {
    __shared__ unsigned short smem[32768];   // 64 KiB: K0|K1|V0|V1, 8192 hw each

    const int i0 = blockIdx.x;
    const int t = threadIdx.x;

    if (i0 >= 512) {                         // residual copy block
        size_t base = (size_t)(i0 - 512) * 2048 + t;
#pragma unroll
        for (int j = 0; j < 4; j++) out4[base + j * 512] = residual4[base + j * 512];
        return;
    }

    int bh, qt;
    if (i0 < 256) { bh = i0 & 31;         qt = 15 - (i0 >> 5); }
    else          { bh = (i0 - 256) & 31; qt = (i0 - 256) >> 5; }
    const int b  = bh >> 4, h = bh & (HH - 1);
    const int q0 = qt * 128;

    const int lane = t & 63;
    const int w = t >> 6;
    const int qsub = w & 3;                  // q-subtile owner (32 rows)
    const int grp  = w >> 2;                 // 0: even kv tiles, 1: odd
    const int l31 = lane & 31;
    const int hi = lane >> 5;

    const unsigned short* qb  = q  + (size_t)bh * SS * DHD;
    const unsigned short* kb  = k  + (size_t)bh * SS * DHD;
    const unsigned short* vtb = vt + (size_t)bh * DHD * SS;

    const int qrow = q0 + qsub * 32 + l31;
    const int fmin = q0 + qsub * 32;

    // Q fragment = B operand of swapped QK^T (Q pre-scaled by 1/8*log2e).
    short8 qf[4];
#pragma unroll
    for (int c = 0; c < 4; c++)
        qf[c] = *(const short8*)(qb + (size_t)qrow * DHD + c * 16 + hi * 8);

    floatx16 o_acc[2];                       // O^T[e = eh*32+crow][q]
#pragma unroll
    for (int eh = 0; eh < 2; eh++)
#pragma unroll
        for (int i = 0; i < 16; i++) o_acc[eh][i] = 0.f;
    float lsum = 0.f;

    // hoisted per-lane LDS read offsets (halfword units)
    int koff[4], voff[4];
#pragma unroll
    for (int c = 0; c < 4; c++)
        koff[c] = (grp * 64 + l31) * 64 + (((2 * c + hi) ^ (l31 & 7)) * 8);
#pragma unroll
    for (int ch = 0; ch < 4; ch++)
        voff[ch] = l31 * 128 + (((grp * 8 + ch * 2 + hi) ^ (l31 & 15)) * 8);

    const int nit = qt + 1;                  // 128-kv iterations

    // prologue: stage iteration 0 into buffer 0
#pragma unroll
    for (int i = 0; i < 2; i++) {
        int u = i * 512 + t, r = u >> 3, c8 = u & 7;
        g2l16(kb + (size_t)r * DHD + (c8 ^ (r & 7)) * 8, smem + u * 8);
    }
#pragma unroll
    for (int i = 0; i < 2; i++) {
        int u = i * 512 + t, e = u >> 4, c16 = u & 15;
        g2l16(vtb + (size_t)e * SS + (c16 ^ (e & 15)) * 8, smem + 16384 + u * 8);
    }

    // ---- main loop: interior iterations, branch-free ----
    for (int it = 0; it < nit - 1; it++) {
        const int cur = it & 1;
        __syncthreads();                     // staging drained + buf reuse safe
        {                                    // prefetch next 128-kv tile (always)
            const int nxt = cur ^ 1;
            const int kbase = (it + 1) * KVT;
#pragma unroll
            for (int i = 0; i < 2; i++) {
                int u = i * 512 + t, r = u >> 3, c8 = u & 7;
                g2l16(kb + (size_t)(kbase + r) * DHD + (c8 ^ (r & 7)) * 8,
                      smem + nxt * 8192 + u * 8);
            }
#pragma unroll
            for (int i = 0; i < 2; i++) {
                int u = i * 512 + t, e = u >> 4, c16 = u & 15;
                g2l16(vtb + (size_t)e * SS + kbase + (c16 ^ (e & 15)) * 8,
                      smem + 16384 + nxt * 8192 + u * 8);
            }
        }

        const unsigned short* Kc = smem + cur * 8192;
        const unsigned short* Vc = smem + 16384 + cur * 8192;

#pragma unroll
        for (int st = 0; st < 2; st++) {
            // S^T[kv][q] = sum_d K[kv][d] * Q[q][d]   (log2 domain)
            floatx16 sacc;
#pragma unroll
            for (int i = 0; i < 16; i++) sacc[i] = 0.f;
            __builtin_amdgcn_s_setprio(1);
#pragma unroll
            for (int c = 0; c < 4; c++) {
                short8 af = *(const short8*)(Kc + st * 2048 + koff[c]);
                sacc = __builtin_amdgcn_mfma_f32_32x32x16_bf16(af, qf[c], sacc,
                                                               0, 0, 0);
            }
            __builtin_amdgcn_s_setprio(0);

            unsigned wv[8];
#pragma unroll
            for (int r2 = 0; r2 < 8; r2++) {
                float p0 = __builtin_amdgcn_exp2f(sacc[2 * r2]);
                float p1 = __builtin_amdgcn_exp2f(sacc[2 * r2 + 1]);
                lsum += p0 + p1;
                wv[r2] = cvt_pk_bf16(p0, p1);
            }
            pl32_swap(wv[0], wv[2]);
            pl32_swap(wv[1], wv[3]);
            pl32_swap(wv[4], wv[6]);
            pl32_swap(wv[5], wv[7]);
            union { unsigned u[4]; short8 s; } u0, u1;
            u0.u[0] = wv[0]; u0.u[1] = wv[1]; u0.u[2] = wv[2]; u0.u[3] = wv[3];
            u1.u[0] = wv[4]; u1.u[1] = wv[5]; u1.u[2] = wv[6]; u1.u[3] = wv[7];
            const short8 pb0 = u0.s, pb1 = u1.s;

            // O^T += V^T * P^T for this subtile's 32 kv
            __builtin_amdgcn_s_setprio(1);
#pragma unroll
            for (int eh = 0; eh < 2; eh++) {
                short8 vf0 = *(const short8*)(Vc + eh * 4096 + voff[2 * st]);
                o_acc[eh] = __builtin_amdgcn_mfma_f32_32x32x16_bf16(
                    vf0, pb0, o_acc[eh], 0, 0, 0);
                short8 vf1 = *(const short8*)(Vc + eh * 4096 + voff[2 * st + 1]);
                o_acc[eh] = __builtin_amdgcn_mfma_f32_32x32x16_bf16(
                    vf1, pb1, o_acc[eh], 0, 0, 0);
            }
            __builtin_amdgcn_s_setprio(0);
        }
    }

    // ---- peeled last iteration (it == qt): diagonal + alive handling ----
    {
        const int it = nit - 1;
        const int cur = it & 1;
        __syncthreads();                     // last tile staged; buf reuse safe
        const unsigned short* Kc = smem + cur * 8192;
        const unsigned short* Vc = smem + 16384 + cur * 8192;
        const int tb = it * KVT + grp * 64;

#pragma unroll
        for (int st = 0; st < 2; st++) {
            const int kvb = tb + st * 32;
            if (kvb > fmin + 31) continue;   // dead subtile (wave-uniform)

            floatx16 sacc;
#pragma unroll
            for (int i = 0; i < 16; i++) sacc[i] = 0.f;
            __builtin_amdgcn_s_setprio(1);
#pragma unroll
            for (int c = 0; c < 4; c++) {
                short8 af = *(const short8*)(Kc + st * 2048 + koff[c]);
                sacc = __builtin_amdgcn_mfma_f32_32x32x16_bf16(af, qf[c], sacc,
                                                               0, 0, 0);
            }
            __builtin_amdgcn_s_setprio(0);

            unsigned wv[8];
            if (kvb + 31 <= fmin) {          // interior subtile in last tile
#pragma unroll
                for (int r2 = 0; r2 < 8; r2++) {
                    float p0 = __builtin_amdgcn_exp2f(sacc[2 * r2]);
                    float p1 = __builtin_amdgcn_exp2f(sacc[2 * r2 + 1]);
                    lsum += p0 + p1;
                    wv[r2] = cvt_pk_bf16(p0, p1);
                }
            } else {                         // diagonal subtile
#pragma unroll
                for (int r2 = 0; r2 < 8; r2++) {
                    const int ra = 2 * r2, rb = 2 * r2 + 1;
                    const int kva = kvb + (ra & 3) + 8 * (ra >> 2) + 4 * hi;
                    const int kvc = kvb + (rb & 3) + 8 * (rb >> 2) + 4 * hi;
                    float p0 = (kva <= qrow) ? __builtin_amdgcn_exp2f(sacc[ra]) : 0.f;
                    float p1 = (kvc <= qrow) ? __builtin_amdgcn_exp2f(sacc[rb]) : 0.f;
                    lsum += p0 + p1;
                    wv[r2] = cvt_pk_bf16(p0, p1);
                }
            }
            pl32_swap(wv[0], wv[2]);
            pl32_swap(wv[1], wv[3]);
            pl32_swap(wv[4], wv[6]);
            pl32_swap(wv[5], wv[7]);
            union { unsigned u[4]; short8 s; } u0, u1;
            u0.u[0] = wv[0]; u0.u[1] = wv[1]; u0.u[2] = wv[2]; u0.u[3] = wv[3];
            u1.u[0] = wv[4]; u1.u[1] = wv[5]; u1.u[2] = wv[6]; u1.u[3] = wv[7];
            const short8 pb0 = u0.s, pb1 = u1.s;

            __builtin_amdgcn_s_setprio(1);
#pragma unroll
            for (int eh = 0; eh < 2; eh++) {
                short8 vf0 = *(const short8*)(Vc + eh * 4096 + voff[2 * st]);
                o_acc[eh] = __builtin_amdgcn_mfma_f32_32x32x16_bf16(
                    vf0, pb0, o_acc[eh], 0, 0, 0);
                short8 vf1 = *(const short8*)(Vc + eh * 4096 + voff[2 * st + 1]);
                o_acc[eh] = __builtin_amdgcn_mfma_f32_32x32x16_bf16(
                    vf1, pb1, o_acc[eh], 0, 0, 0);
            }
            __builtin_amdgcn_s_setprio(0);
        }
    }

    // combine hi/lo kv-halves within wave, then wave-pair partials via LDS
    lsum += __shfl_xor(lsum, 32);
    float* cm = (float*)smem;
    float* slot = cm + (qsub * 64 + lane) * 33;   // stride 33 -> conflict-free
    __syncthreads();
    if (grp == 1) {
#pragma unroll
        for (int eh = 0; eh < 2; eh++)
#pragma unroll
            for (int i = 0; i < 16; i++) slot[eh * 16 + i] = o_acc[eh][i];
        slot[32] = lsum;
    }
    __syncthreads();
    if (grp == 0) {
#pragma unroll
        for (int eh = 0; eh < 2; eh++)
#pragma unroll
            for (int i = 0; i < 16; i++) o_acc[eh][i] += slot[eh * 16 + i];
        const float inv = 1.f / (lsum + slot[32]);
        unsigned short* zr = z + ((size_t)b * SS + qrow) * (HH * DHD) + h * DHD;
#pragma unroll
        for (int eh = 0; eh < 2; eh++)
#pragma unroll
            for (int g = 0; g < 4; g++) {
                ushortx4 o;
#pragma unroll
                for (int m = 0; m < 4; m++) o[m] = f2bf(o_acc[eh][g * 4 + m] * inv);
                *(ushortx4*)(zr + eh * 32 + g * 8 + 4 * hi) = o;
            }
    }
}

// ---------------------------------------------------------------------------
// O-proj MFMA GEMM (round-9 proven form, unchanged): 64x64 tiles + 2-phase
// dbuf prefetch, 32 KB LDS, grid (64,16) = 1024 blocks.
// ---------------------------------------------------------------------------
__global__ __launch_bounds__(256) void out_mfma(const unsigned short* __restrict__ zb,
        const unsigned short* __restrict__ WtO, const float* __restrict__ bo,
        float* __restrict__ out) {
    __shared__ unsigned short smem[16384];         // A0|A1|B0|B1, 4096 hw each

    const int m0 = blockIdx.x * 64;
    const int n0 = blockIdx.y * 64;
    const int t = threadIdx.x;
    const int lane = t & 63, w = t >> 6;
    const int l15 = lane & 15, quad = lane >> 4;

    floatx4 acc[4];
#pragma unroll
    for (int nt = 0; nt < 4; nt++) acc[nt] = floatx4{0.f, 0.f, 0.f, 0.f};

    // prologue: stage k0=0 into buffer 0
#pragma unroll
    for (int i = 0; i < 2; i++) {
        int c = i * 256 + t;
        int row = c >> 3, c8 = c & 7;
        g2l16(zb + (size_t)(m0 + row) * DD + SW(row, c8) * 8, smem + c * 8);
        g2l16(WtO + (size_t)(n0 + row) * DD + SW(row, c8) * 8, smem + 8192 + c * 8);
    }

    int buf = 0;
    for (int k0 = 0; k0 < DD; k0 += 64) {
        __syncthreads();
        if (k0 + 64 < DD) {
            const int nb = buf ^ 1;
#pragma unroll
            for (int i = 0; i < 2; i++) {
                int c = i * 256 + t;
                int row = c >> 3, c8 = c & 7;
                g2l16(zb + (size_t)(m0 + row) * DD + k0 + 64 + SW(row, c8) * 8,
                      smem + nb * 4096 + c * 8);
                g2l16(WtO + (size_t)(n0 + row) * DD + k0 + 64 + SW(row, c8) * 8,
                      smem + 8192 + nb * 4096 + c * 8);
            }
        }
        const unsigned short* As = smem + buf * 4096;
        const unsigned short* Bs = smem + 8192 + buf * 4096;
#pragma unroll
        for (int ks = 0; ks < 2; ks++) {
            short8 af = *(const short8*)(As + (w * 16 + l15) * 64 +
                                         SW(l15, ks * 4 + quad) * 8);
#pragma unroll
            for (int nt = 0; nt < 4; nt++) {
                short8 bf = *(const short8*)(Bs + (nt * 16 + l15) * 64 +
                                             SW(l15, ks * 4 + quad) * 8);
                acc[nt] = __builtin_amdgcn_mfma_f32_16x16x32_bf16(
                    af, bf, acc[nt], 0, 0, 0);
            }
        }
        buf ^= 1;
    }
#pragma unroll
    for (int r = 0; r < 4; r++) {
        int m = m0 + w * 16 + quad * 4 + r;
#pragma unroll
        for (int nt = 0; nt < 4; nt++) {
            int n = n0 + nt * 16 + l15;
            out[(size_t)m * DD + n] = acc[nt][r] + bo[n];
        }
    }
}

extern "C" void kernel_launch(void* const* d_in, const int* in_sizes, int n_in,
                              void* d_out, int out_size, void* d_ws, size_t ws_size,
                              hipStream_t stream) {
    const float* residual = (const float*)d_in[0];
    const float* x   = (const float*)d_in[1];
    const float* W_Q = (const float*)d_in[2];
    const float* W_K = (const float*)d_in[3];
    const float* W_V = (const float*)d_in[4];
    const float* W_O = (const float*)d_in[5];
    const float* b_Q = (const float*)d_in[6];
    const float* b_K = (const float*)d_in[7];
    const float* b_V = (const float*)d_in[8];
    const float* b_O = (const float*)d_in[9];
    float* out = (float*)d_out;

    const size_t NE = (size_t)BB * SS * HH * DHD;
    unsigned short* xb  = (unsigned short*)d_ws;
    unsigned short* Wt  = xb + (size_t)4096 * 1024;
    unsigned short* WtO = Wt + (size_t)3072 * 1024;
    unsigned short* qb  = WtO + (size_t)1024 * 1024;
    unsigned short* kb  = qb + NE;
    unsigned short* vb  = kb + NE;          // [B][H][64][S] (pre-transposed)
    unsigned short* zb  = vb + NE;

    prep<<<3072, 256, 0, stream>>>(x, xb, W_Q, W_K, W_V, Wt, W_O, WtO);

    qkv_mfma<<<dim3(32, 24), 256, 0, stream>>>(xb, Wt, b_Q, b_K, b_V, qb, kb, vb);

    attn<<<1024, 512, 0, stream>>>(qb, kb, vb, zb,
                                   (const float4*)residual, (float4*)out);

    out_mfma<<<dim3(64, 16), 256, 0, stream>>>(
        zb, WtO, b_O, out + (size_t)BB * SS * DD);
}

// Round 11
// 171.402 us; speedup vs baseline: 1.0302x; 1.0302x over previous
//
#include <hip/hip_runtime.h>
#include <hip/hip_bf16.h>

#define BB 2
#define SS 2048
#define DD 1024
#define HH 16
#define DHD 64

typedef __attribute__((ext_vector_type(8))) short short8;   // 8 bf16 = 4 VGPRs
typedef __attribute__((ext_vector_type(4))) float floatx4;  // MFMA 16x16 C/D
typedef __attribute__((ext_vector_type(16))) float floatx16; // MFMA 32x32 C/D
typedef __attribute__((ext_vector_type(4))) unsigned short ushortx4;

static __device__ __forceinline__ unsigned short f2bf(float f) {
    union { __hip_bfloat16 h; unsigned short u; } cv;
    cv.h = __float2bfloat16(f);
    return cv.u;
}

// async global->LDS 16B copy; LDS dest MUST be wave-uniform base + lane*16
typedef __attribute__((address_space(1))) const unsigned int* gas_t;
typedef __attribute__((address_space(3))) unsigned int* las_t;
static __device__ __forceinline__ void g2l16(const void* g, void* l) {
    __builtin_amdgcn_global_load_lds((gas_t)g, (las_t)l, 16, 0, 0);
}

// XOR swizzle: LDS[row][c8] holds global[row][c8 ^ (row&7)] (c8 = 16B chunk).
#define SW(row, c8) ((c8) ^ ((row) & 7))

// pack 2 f32 -> 1 u32 of 2 bf16 (no builtin on gfx950; T12 recipe)
static __device__ __forceinline__ unsigned cvt_pk_bf16(float lo, float hi) {
    unsigned r;
    asm("v_cvt_pk_bf16_f32 %0, %1, %2" : "=v"(r) : "v"(lo), "v"(hi));
    return r;
}
static __device__ __forceinline__ void pl32_swap(unsigned &a, unsigned &b) {
    asm("v_permlane32_swap_b32 %0, %1" : "+v"(a), "+v"(b));
}

// ---------------------------------------------------------------------------
// Fused prep kernel (round-9 form: residual copy restored).
// ---------------------------------------------------------------------------
__global__ __launch_bounds__(256) void prep(const float4* __restrict__ residual4,
        float4* __restrict__ out4,
        const float* __restrict__ x, unsigned short* __restrict__ xb,
        const float* __restrict__ WQ, const float* __restrict__ WK,
        const float* __restrict__ WV, unsigned short* __restrict__ Wt,
        const float* __restrict__ WO, unsigned short* __restrict__ WtO) {
    __shared__ float tile[64][65];
    const int bid = blockIdx.x;
    const int t = threadIdx.x;

    if (bid < 1024) {                              // residual copy
        size_t base = (size_t)bid * 1024 + t;
#pragma unroll
        for (int j = 0; j < 4; j++) out4[base + j * 256] = residual4[base + j * 256];
    } else if (bid < 3072) {                       // x -> bf16
        size_t i = ((size_t)(bid - 1024) * 256 + t) * 8;
        const float4* src4 = (const float4*)(x + i);
        float4 a = src4[0], b = src4[1];
        short8 o;
        o[0] = (short)f2bf(a.x); o[1] = (short)f2bf(a.y);
        o[2] = (short)f2bf(a.z); o[3] = (short)f2bf(a.w);
        o[4] = (short)f2bf(b.x); o[5] = (short)f2bf(b.y);
        o[6] = (short)f2bf(b.z); o[7] = (short)f2bf(b.w);
        *(short8*)(xb + i) = o;
    } else if (bid < 3840) {                       // W_QKV transpose
        int u = bid - 3072;
        const int d0 = (u & 15) * 64;
        const int h  = (u >> 4) & 15;
        const int which = u >> 8;
        const float* W = (which == 0) ? WQ : (which == 1) ? WK : WV;
        const float* src = W + (size_t)h * DD * DHD;
#pragma unroll
        for (int i = 0; i < 16; i++) {
            int idx = i * 256 + t;
            int r = idx >> 6, c = idx & 63;
            tile[r][c] = src[(size_t)(d0 + r) * DHD + c];
        }
        __syncthreads();
        unsigned short* dst = Wt + ((size_t)which * 1024 + h * 64) * DD;
#pragma unroll
        for (int i = 0; i < 16; i++) {
            int idx = i * 256 + t;
            int e = idx >> 6, d = idx & 63;
            dst[(size_t)e * DD + d0 + d] = f2bf(tile[d][e]);
        }
    } else {                                       // W_O transpose
        int u = bid - 3840;
        const int k0 = (u & 15) * 64;
        const int n0 = (u >> 4) * 64;
#pragma unroll
        for (int i = 0; i < 16; i++) {
            int idx = i * 256 + t;
            int r = idx >> 6, c = idx & 63;
            tile[r][c] = WO[(size_t)(k0 + r) * DD + n0 + c];
        }
        __syncthreads();
#pragma unroll
        for (int i = 0; i < 16; i++) {
            int idx = i * 256 + t;
            int n = idx >> 6, kk = idx & 63;
            WtO[(size_t)(n0 + n) * DD + k0 + kk] = f2bf(tile[kk][n]);
        }
    }
}

// ---------------------------------------------------------------------------
// QKV MFMA GEMM (round-9 proven form): 128x128 tiles, 2-phase double-buffered
// prefetch, one __syncthreads per K-step. Q pre-scale folds log2(e):
// 0.125 * 1.4426950 = 0.18033688.
// ---------------------------------------------------------------------------
__global__ __launch_bounds__(256) void qkv_mfma(const unsigned short* __restrict__ xb,
        const unsigned short* __restrict__ Wt,
        const float* __restrict__ bQ, const float* __restrict__ bK,
        const float* __restrict__ bV,
        unsigned short* __restrict__ oq, unsigned short* __restrict__ ok,
        unsigned short* __restrict__ ov) {
    __shared__ unsigned short smem[32768];         // A0|A1|B0|B1, 8192 hw each

    const int m0 = blockIdx.x * 128;
    const int y  = blockIdx.y;
    const int which = y >> 3;
    const int h0 = (y & 7) * 2;
    const float* bias = (which == 0) ? bQ : (which == 1) ? bK : bV;
    unsigned short* ob = (which == 0) ? oq : (which == 1) ? ok : ov;
    const float scale = (which == 0) ? 0.18033688f : 1.0f;  // 1/8 * log2(e)
    const unsigned short* Wb = Wt + (size_t)y * 128 * DD;

    const int t = threadIdx.x;
    const int lane = t & 63, w = t >> 6;
    const int l15 = lane & 15, quad = lane >> 4;

    floatx4 acc[2][8];
#pragma unroll
    for (int mt = 0; mt < 2; mt++)
#pragma unroll
        for (int nt = 0; nt < 8; nt++) acc[mt][nt] = floatx4{0.f, 0.f, 0.f, 0.f};

    // prologue: stage k0=0 into buffer 0
#pragma unroll
    for (int i = 0; i < 4; i++) {
        int c = i * 256 + t;
        int row = c >> 3, c8 = c & 7;
        g2l16(xb + (size_t)(m0 + row) * DD + SW(row, c8) * 8, smem + c * 8);
        g2l16(Wb + (size_t)row * DD + SW(row, c8) * 8, smem + 16384 + c * 8);
    }

    int buf = 0;
    for (int k0 = 0; k0 < DD; k0 += 64) {
        __syncthreads();                           // tile k0 staged; buf reuse safe
        if (k0 + 64 < DD) {                        // prefetch k0+64 under compute
            const int nb = buf ^ 1;
#pragma unroll
            for (int i = 0; i < 4; i++) {
                int c = i * 256 + t;
                int row = c >> 3, c8 = c & 7;
                g2l16(xb + (size_t)(m0 + row) * DD + k0 + 64 + SW(row, c8) * 8,
                      smem + nb * 8192 + c * 8);
                g2l16(Wb + (size_t)row * DD + k0 + 64 + SW(row, c8) * 8,
                      smem + 16384 + nb * 8192 + c * 8);
            }
        }
        const unsigned short* As = smem + buf * 8192;
        const unsigned short* Bs = smem + 16384 + buf * 8192;
#pragma unroll
        for (int ks = 0; ks < 2; ks++) {
            short8 af[2], bf[8];
#pragma unroll
            for (int mt = 0; mt < 2; mt++)
                af[mt] = *(const short8*)(As + (w * 32 + mt * 16 + l15) * 64 +
                                          SW(l15, ks * 4 + quad) * 8);
#pragma unroll
            for (int nt = 0; nt < 8; nt++)
                bf[nt] = *(const short8*)(Bs + (nt * 16 + l15) * 64 +
                                          SW(l15, ks * 4 + quad) * 8);
#pragma unroll
            for (int mt = 0; mt < 2; mt++)
#pragma unroll
                for (int nt = 0; nt < 8; nt++)
                    acc[mt][nt] = __builtin_amdgcn_mfma_f32_16x16x32_bf16(
                        af[mt], bf[nt], acc[mt][nt], 0, 0, 0);
        }
        buf ^= 1;
    }
    __syncthreads();                               // before epilogue LDS reuse

    if (which == 2) {
        // V: transpose block tile in LDS, store V^T [B][H][64][S] coalesced.
        unsigned short* T = smem;                  // 128(n) x 132 stride
#pragma unroll
        for (int mt = 0; mt < 2; mt++)
#pragma unroll
            for (int r = 0; r < 4; r++) {
                int mloc = w * 32 + mt * 16 + quad * 4 + r;
#pragma unroll
                for (int nt = 0; nt < 8; nt++) {
                    int n = nt * 16 + l15;
                    int h = h0 + (n >> 6), e = n & 63;
                    T[n * 132 + mloc] = f2bf(acc[mt][nt][r] + bias[h * DHD + e]);
                }
            }
        __syncthreads();
        const int b = m0 >> 11;
        const int s_base = m0 & (SS - 1);
#pragma unroll
        for (int i = 0; i < 8; i++) {
            int u = i * 256 + t;
            int row = u >> 4, c8 = u & 15;
            int h = h0 + (row >> 6), e = row & 63;
            *(short8*)(ov + (((size_t)b * HH + h) * DHD + e) * SS + s_base + c8 * 8) =
                *(const short8*)(T + row * 132 + c8 * 8);
        }
    } else {
#pragma unroll
        for (int mt = 0; mt < 2; mt++) {
#pragma unroll
            for (int r = 0; r < 4; r++) {
                int m = m0 + w * 32 + mt * 16 + quad * 4 + r;
                int b = m >> 11, s = m & (SS - 1);
#pragma unroll
                for (int nt = 0; nt < 8; nt++) {
                    int h = h0 + (nt >> 2);
                    int e = (nt & 3) * 16 + l15;
                    float v = (acc[mt][nt][r] + bias[h * DHD + e]) * scale;
                    ob[(((size_t)b * HH + h) * SS + s) * DHD + e] = f2bf(v);
                }
            }
        }
    }
}

// ---------------------------------------------------------------------------
// MFMA flash attention (round-9 proven form): LDS-staged 2-phase dbuf,
// in-register softmax (swapped 32x32 QK^T, cvt_pk+permlane), setprio MFMA
// clusters, exp2-direct, diagonal-iteration peel (main loop branch-free).
// ---------------------------------------------------------------------------
#define KVT 128
__global__ __launch_bounds__(512, 4) void attn(const unsigned short* __restrict__ q,
        const unsigned short* __restrict__ k, const unsigned short* __restrict__ vt,
        unsigned short* __restrict__ z) {
    __shared__ unsigned short smem[32768];   // 64 KiB: K0|K1|V0|V1, 8192 hw each

    const int i0 = blockIdx.x;
    int bh, qt;
    if (i0 < 256) { bh = i0 & 31;         qt = 15 - (i0 >> 5); }
    else          { bh = (i0 - 256) & 31; qt = (i0 - 256) >> 5; }
    const int b  = bh >> 4, h = bh & (HH - 1);
    const int q0 = qt * 128;

    const int t = threadIdx.x;
    const int lane = t & 63;
    const int w = t >> 6;
    const int qsub = w & 3;                  // q-subtile owner (32 rows)
    const int grp  = w >> 2;                 // 0: even kv tiles, 1: odd
    const int l31 = lane & 31;
    const int hi = lane >> 5;

    const unsigned short* qb  = q  + (size_t)bh * SS * DHD;
    const unsigned short* kb  = k  + (size_t)bh * SS * DHD;
    const unsigned short* vtb = vt + (size_t)bh * DHD * SS;

    const int qrow = q0 + qsub * 32 + l31;
    const int fmin = q0 + qsub * 32;

    // Q fragment = B operand of swapped QK^T (Q pre-scaled by 1/8*log2e).
    short8 qf[4];
#pragma unroll
    for (int c = 0; c < 4; c++)
        qf[c] = *(const short8*)(qb + (size_t)qrow * DHD + c * 16 + hi * 8);

    floatx16 o_acc[2];                       // O^T[e = eh*32+crow][q]
#pragma unroll
    for (int eh = 0; eh < 2; eh++)
#pragma unroll
        for (int i = 0; i < 16; i++) o_acc[eh][i] = 0.f;
    float lsum = 0.f;

    // hoisted per-lane LDS read offsets (halfword units)
    int koff[4], voff[4];
#pragma unroll
    for (int c = 0; c < 4; c++)
        koff[c] = (grp * 64 + l31) * 64 + (((2 * c + hi) ^ (l31 & 7)) * 8);
#pragma unroll
    for (int ch = 0; ch < 4; ch++)
        voff[ch] = l31 * 128 + (((grp * 8 + ch * 2 + hi) ^ (l31 & 15)) * 8);

    const int nit = qt + 1;                  // 128-kv iterations

    // prologue: stage iteration 0 into buffer 0
#pragma unroll
    for (int i = 0; i < 2; i++) {
        int u = i * 512 + t, r = u >> 3, c8 = u & 7;
        g2l16(kb + (size_t)r * DHD + (c8 ^ (r & 7)) * 8, smem + u * 8);
    }
#pragma unroll
    for (int i = 0; i < 2; i++) {
        int u = i * 512 + t, e = u >> 4, c16 = u & 15;
        g2l16(vtb + (size_t)e * SS + (c16 ^ (e & 15)) * 8, smem + 16384 + u * 8);
    }

    // ---- main loop: interior iterations, branch-free ----
    for (int it = 0; it < nit - 1; it++) {
        const int cur = it & 1;
        __syncthreads();                     // staging drained + buf reuse safe
        {                                    // prefetch next 128-kv tile (always)
            const int nxt = cur ^ 1;
            const int kbase = (it + 1) * KVT;
#pragma unroll
            for (int i = 0; i < 2; i++) {
                int u = i * 512 + t, r = u >> 3, c8 = u & 7;
                g2l16(kb + (size_t)(kbase + r) * DHD + (c8 ^ (r & 7)) * 8,
                      smem + nxt * 8192 + u * 8);
            }
#pragma unroll
            for (int i = 0; i < 2; i++) {
                int u = i * 512 + t, e = u >> 4, c16 = u & 15;
                g2l16(vtb + (size_t)e * SS + kbase + (c16 ^ (e & 15)) * 8,
                      smem + 16384 + nxt * 8192 + u * 8);
            }
        }

        const unsigned short* Kc = smem + cur * 8192;
        const unsigned short* Vc = smem + 16384 + cur * 8192;

#pragma unroll
        for (int st = 0; st < 2; st++) {
            // S^T[kv][q] = sum_d K[kv][d] * Q[q][d]   (log2 domain)
            floatx16 sacc;
#pragma unroll
            for (int i = 0; i < 16; i++) sacc[i] = 0.f;
            __builtin_amdgcn_s_setprio(1);
#pragma unroll
            for (int c = 0; c < 4; c++) {
                short8 af = *(const short8*)(Kc + st * 2048 + koff[c]);
                sacc = __builtin_amdgcn_mfma_f32_32x32x16_bf16(af, qf[c], sacc,
                                                               0, 0, 0);
            }
            __builtin_amdgcn_s_setprio(0);

            unsigned wv[8];
#pragma unroll
            for (int r2 = 0; r2 < 8; r2++) {
                float p0 = __builtin_amdgcn_exp2f(sacc[2 * r2]);
                float p1 = __builtin_amdgcn_exp2f(sacc[2 * r2 + 1]);
                lsum += p0 + p1;
                wv[r2] = cvt_pk_bf16(p0, p1);
            }
            pl32_swap(wv[0], wv[2]);
            pl32_swap(wv[1], wv[3]);
            pl32_swap(wv[4], wv[6]);
            pl32_swap(wv[5], wv[7]);
            union { unsigned u[4]; short8 s; } u0, u1;
            u0.u[0] = wv[0]; u0.u[1] = wv[1]; u0.u[2] = wv[2]; u0.u[3] = wv[3];
            u1.u[0] = wv[4]; u1.u[1] = wv[5]; u1.u[2] = wv[6]; u1.u[3] = wv[7];
            const short8 pb0 = u0.s, pb1 = u1.s;

            // O^T += V^T * P^T for this subtile's 32 kv
            __builtin_amdgcn_s_setprio(1);
#pragma unroll
            for (int eh = 0; eh < 2; eh++) {
                short8 vf0 = *(const short8*)(Vc + eh * 4096 + voff[2 * st]);
                o_acc[eh] = __builtin_amdgcn_mfma_f32_32x32x16_bf16(
                    vf0, pb0, o_acc[eh], 0, 0, 0);
                short8 vf1 = *(const short8*)(Vc + eh * 4096 + voff[2 * st + 1]);
                o_acc[eh] = __builtin_amdgcn_mfma_f32_32x32x16_bf16(
                    vf1, pb1, o_acc[eh], 0, 0, 0);
            }
            __builtin_amdgcn_s_setprio(0);
        }
    }

    // ---- peeled last iteration (it == qt): diagonal + alive handling ----
    {
        const int it = nit - 1;
        const int cur = it & 1;
        __syncthreads();                     // last tile staged; buf reuse safe
        const unsigned short* Kc = smem + cur * 8192;
        const unsigned short* Vc = smem + 16384 + cur * 8192;
        const int tb = it * KVT + grp * 64;

#pragma unroll
        for (int st = 0; st < 2; st++) {
            const int kvb = tb + st * 32;
            if (kvb > fmin + 31) continue;   // dead subtile (wave-uniform)

            floatx16 sacc;
#pragma unroll
            for (int i = 0; i < 16; i++) sacc[i] = 0.f;
            __builtin_amdgcn_s_setprio(1);
#pragma unroll
            for (int c = 0; c < 4; c++) {
                short8 af = *(const short8*)(Kc + st * 2048 + koff[c]);
                sacc = __builtin_amdgcn_mfma_f32_32x32x16_bf16(af, qf[c], sacc,
                                                               0, 0, 0);
            }
            __builtin_amdgcn_s_setprio(0);

            unsigned wv[8];
            if (kvb + 31 <= fmin) {          // interior subtile in last tile
#pragma unroll
                for (int r2 = 0; r2 < 8; r2++) {
                    float p0 = __builtin_amdgcn_exp2f(sacc[2 * r2]);
                    float p1 = __builtin_amdgcn_exp2f(sacc[2 * r2 + 1]);
                    lsum += p0 + p1;
                    wv[r2] = cvt_pk_bf16(p0, p1);
                }
            } else {                         // diagonal subtile
#pragma unroll
                for (int r2 = 0; r2 < 8; r2++) {
                    const int ra = 2 * r2, rb = 2 * r2 + 1;
                    const int kva = kvb + (ra & 3) + 8 * (ra >> 2) + 4 * hi;
                    const int kvc = kvb + (rb & 3) + 8 * (rb >> 2) + 4 * hi;
                    float p0 = (kva <= qrow) ? __builtin_amdgcn_exp2f(sacc[ra]) : 0.f;
                    float p1 = (kvc <= qrow) ? __builtin_amdgcn_exp2f(sacc[rb]) : 0.f;
                    lsum += p0 + p1;
                    wv[r2] = cvt_pk_bf16(p0, p1);
                }
            }
            pl32_swap(wv[0], wv[2]);
            pl32_swap(wv[1], wv[3]);
            pl32_swap(wv[4], wv[6]);
            pl32_swap(wv[5], wv[7]);
            union { unsigned u[4]; short8 s; } u0, u1;
            u0.u[0] = wv[0]; u0.u[1] = wv[1]; u0.u[2] = wv[2]; u0.u[3] = wv[3];
            u1.u[0] = wv[4]; u1.u[1] = wv[5]; u1.u[2] = wv[6]; u1.u[3] = wv[7];
            const short8 pb0 = u0.s, pb1 = u1.s;

            __builtin_amdgcn_s_setprio(1);
#pragma unroll
            for (int eh = 0; eh < 2; eh++) {
                short8 vf0 = *(const short8*)(Vc + eh * 4096 + voff[2 * st]);
                o_acc[eh] = __builtin_amdgcn_mfma_f32_32x32x16_bf16(
                    vf0, pb0, o_acc[eh], 0, 0, 0);
                short8 vf1 = *(const short8*)(Vc + eh * 4096 + voff[2 * st + 1]);
                o_acc[eh] = __builtin_amdgcn_mfma_f32_32x32x16_bf16(
                    vf1, pb1, o_acc[eh], 0, 0, 0);
            }
            __builtin_amdgcn_s_setprio(0);
        }
    }

    // combine hi/lo kv-halves within wave, then wave-pair partials via LDS
    lsum += __shfl_xor(lsum, 32);
    float* cm = (float*)smem;
    float* slot = cm + (qsub * 64 + lane) * 33;   // stride 33 -> conflict-free
    __syncthreads();
    if (grp == 1) {
#pragma unroll
        for (int eh = 0; eh < 2; eh++)
#pragma unroll
            for (int i = 0; i < 16; i++) slot[eh * 16 + i] = o_acc[eh][i];
        slot[32] = lsum;
    }
    __syncthreads();
    if (grp == 0) {
#pragma unroll
        for (int eh = 0; eh < 2; eh++)
#pragma unroll
            for (int i = 0; i < 16; i++) o_acc[eh][i] += slot[eh * 16 + i];
        const float inv = 1.f / (lsum + slot[32]);
        unsigned short* zr = z + ((size_t)b * SS + qrow) * (HH * DHD) + h * DHD;
#pragma unroll
        for (int eh = 0; eh < 2; eh++)
#pragma unroll
            for (int g = 0; g < 4; g++) {
                ushortx4 o;
#pragma unroll
                for (int m = 0; m < 4; m++) o[m] = f2bf(o_acc[eh][g * 4 + m] * inv);
                *(ushortx4*)(zr + eh * 32 + g * 8 + 4 * hi) = o;
            }
    }
}

// ---------------------------------------------------------------------------
// O-proj MFMA GEMM (round-9 proven form): 64x64 tiles + 2-phase dbuf
// prefetch, 32 KB LDS, grid (64,16) = 1024 blocks.
// ---------------------------------------------------------------------------
__global__ __launch_bounds__(256) void out_mfma(const unsigned short* __restrict__ zb,
        const unsigned short* __restrict__ WtO, const float* __restrict__ bo,
        float* __restrict__ out) {
    __shared__ unsigned short smem[16384];         // A0|A1|B0|B1, 4096 hw each

    const int m0 = blockIdx.x * 64;
    const int n0 = blockIdx.y * 64;
    const int t = threadIdx.x;
    const int lane = t & 63, w = t >> 6;
    const int l15 = lane & 15, quad = lane >> 4;

    floatx4 acc[4];
#pragma unroll
    for (int nt = 0; nt < 4; nt++) acc[nt] = floatx4{0.f, 0.f, 0.f, 0.f};

    // prologue: stage k0=0 into buffer 0
#pragma unroll
    for (int i = 0; i < 2; i++) {
        int c = i * 256 + t;
        int row = c >> 3, c8 = c & 7;
        g2l16(zb + (size_t)(m0 + row) * DD + SW(row, c8) * 8, smem + c * 8);
        g2l16(WtO + (size_t)(n0 + row) * DD + SW(row, c8) * 8, smem + 8192 + c * 8);
    }

    int buf = 0;
    for (int k0 = 0; k0 < DD; k0 += 64) {
        __syncthreads();
        if (k0 + 64 < DD) {
            const int nb = buf ^ 1;
#pragma unroll
            for (int i = 0; i < 2; i++) {
                int c = i * 256 + t;
                int row = c >> 3, c8 = c & 7;
                g2l16(zb + (size_t)(m0 + row) * DD + k0 + 64 + SW(row, c8) * 8,
                      smem + nb * 4096 + c * 8);
                g2l16(WtO + (size_t)(n0 + row) * DD + k0 + 64 + SW(row, c8) * 8,
                      smem + 8192 + nb * 4096 + c * 8);
            }
        }
        const unsigned short* As = smem + buf * 4096;
        const unsigned short* Bs = smem + 8192 + buf * 4096;
#pragma unroll
        for (int ks = 0; ks < 2; ks++) {
            short8 af = *(const short8*)(As + (w * 16 + l15) * 64 +
                                         SW(l15, ks * 4 + quad) * 8);
#pragma unroll
            for (int nt = 0; nt < 4; nt++) {
                short8 bf = *(const short8*)(Bs + (nt * 16 + l15) * 64 +
                                             SW(l15, ks * 4 + quad) * 8);
                acc[nt] = __builtin_amdgcn_mfma_f32_16x16x32_bf16(
                    af, bf, acc[nt], 0, 0, 0);
            }
        }
        buf ^= 1;
    }
#pragma unroll
    for (int r = 0; r < 4; r++) {
        int m = m0 + w * 16 + quad * 4 + r;
#pragma unroll
        for (int nt = 0; nt < 4; nt++) {
            int n = n0 + nt * 16 + l15;
            out[(size_t)m * DD + n] = acc[nt][r] + bo[n];
        }
    }
}

extern "C" void kernel_launch(void* const* d_in, const int* in_sizes, int n_in,
                              void* d_out, int out_size, void* d_ws, size_t ws_size,
                              hipStream_t stream) {
    const float* residual = (const float*)d_in[0];
    const float* x   = (const float*)d_in[1];
    const float* W_Q = (const float*)d_in[2];
    const float* W_K = (const float*)d_in[3];
    const float* W_V = (const float*)d_in[4];
    const float* W_O = (const float*)d_in[5];
    const float* b_Q = (const float*)d_in[6];
    const float* b_K = (const float*)d_in[7];
    const float* b_V = (const float*)d_in[8];
    const float* b_O = (const float*)d_in[9];
    float* out = (float*)d_out;

    const size_t NE = (size_t)BB * SS * HH * DHD;
    unsigned short* xb  = (unsigned short*)d_ws;
    unsigned short* Wt  = xb + (size_t)4096 * 1024;
    unsigned short* WtO = Wt + (size_t)3072 * 1024;
    unsigned short* qb  = WtO + (size_t)1024 * 1024;
    unsigned short* kb  = qb + NE;
    unsigned short* vb  = kb + NE;          // [B][H][64][S] (pre-transposed)
    unsigned short* zb  = vb + NE;

    prep<<<4096, 256, 0, stream>>>((const float4*)residual, (float4*)out,
                                   x, xb, W_Q, W_K, W_V, Wt, W_O, WtO);

    qkv_mfma<<<dim3(32, 24), 256, 0, stream>>>(xb, Wt, b_Q, b_K, b_V, qb, kb, vb);

    attn<<<512, 512, 0, stream>>>(qb, kb, vb, zb);

    out_mfma<<<dim3(64, 16), 256, 0, stream>>>(
        zb, WtO, b_O, out + (size_t)BB * SS * DD);
}